// Round 8
// baseline (243.169 us; speedup 1.0000x reference)
//
#include <hip/hip_runtime.h>

#define NT 2048            // number of distinct event times
#define HB 1024            // hist blocks (4 per CU)
#define HT 512             // hist threads per block (8 waves)
#define RB 256             // reduce blocks (8 bins each)
#define RT 1024
#define EB 128             // efron blocks (16 bins each, 1 wave per bin)
#define ET 1024

#define SC      4096.0f              // 2^12 fixed-point scale (exact pow2 mult)
#define INV_SC  (1.0 / 4096.0)
#define TM26    ((1u << 26) - 1)     // tn pack: low 26 bits T, high 6 bits count
#define INV32   (1.0 / 4294967296.0)

typedef unsigned long long u64;
typedef unsigned u32;

__device__ __forceinline__ double wave_reduce(double v) {
#pragma unroll
    for (int o = 32; o > 0; o >>= 1) v += __shfl_down(v, o, 64);
    return v;
}

// ---------------------------------------------------------------------------
// K1: LDS histogram at 32 waves/CU (4 blocks x 8 waves, <=64 VGPR).
// Exactly 2 vec4 iterations per thread, all 6x16B loads staged up front.
// One u32 LDS atomic per sample: loc[d + e*NT] += fx + (e<<26).
// hr*e / e sums: per-wave shuffle reduce -> ONE u64 fixed-point global atomic
// per wave (integer = deterministic).
// ---------------------------------------------------------------------------
__global__ __launch_bounds__(HT, 8) void k_hist(
    const float* __restrict__ hr, const int* __restrict__ dur,
    const int* __restrict__ ev, int n,
    u32* __restrict__ s0_part, u32* __restrict__ tn_part,
    u64* __restrict__ hrE_cell, u64* __restrict__ ec_cell)
{
    __shared__ u32 loc[2 * NT];      // 16 KB

    const int tid = threadIdx.x, bid = blockIdx.x;

    for (int i = tid; i < 2 * NT; i += HT) loc[i] = 0u;
    __syncthreads();

    float hrE = 0.f;
    int   ec  = 0;
    const int stride = HB * HT;      // 524288
    const int nv = n >> 2;           // 1048576
    const float4* hr4 = (const float4*)hr;
    const int4*   d4p = (const int4*)dur;
    const int4*   e4p = (const int4*)ev;

    auto process = [&](const float4& h, const int4& d, const int4& e) {
        float hh[4] = { h.x, h.y, h.z, h.w };
        int   dd[4] = { d.x, d.y, d.z, d.w };
        int   ee[4] = { e.x, e.y, e.z, e.w };
#pragma unroll
        for (int u = 0; u < 4; ++u) {
            float eh = __expf(hh[u]);
            u32 fx = (u32)(eh * SC + 0.5f);
            atomicAdd(&loc[dd[u] + (ee[u] << 11)], fx + ((u32)ee[u] << 26));
            hrE += hh[u] * (float)ee[u];
            ec  += ee[u];
        }
    };

    // n = 2^22: exactly 2 vec4 iterations per thread; stage ALL loads first.
    {
        int i0 = bid * HT + tid;
        int i1 = i0 + stride;
        if (i1 < nv) {                       // common case: both iterations
            float4 h0 = hr4[i0]; int4 d0 = d4p[i0]; int4 e0 = e4p[i0];
            float4 h1 = hr4[i1]; int4 d1 = d4p[i1]; int4 e1 = e4p[i1];
            process(h0, d0, e0);
            process(h1, d1, e1);
        } else {
            for (int i = i0; i < nv; i += stride)
                process(hr4[i], d4p[i], e4p[i]);
        }
    }
    for (int j = (nv << 2) + bid * HT + tid; j < n; j += stride) {  // tail
        float h = hr[j]; int d = dur[j]; int e = ev[j];
        atomicAdd(&loc[d + (e << 11)], (u32)(__expf(h) * SC + 0.5f) + ((u32)e << 26));
        hrE += h * (float)e;
        ec  += e;
    }
    __syncthreads();

    // write per-block partial rows (streaming, coalesced)
    const size_t base = (size_t)bid * NT;
    for (int k = tid; k < NT; k += HT) {
        s0_part[base + k] = loc[k];
        tn_part[base + k] = loc[NT + k];
    }

    // per-wave deterministic fixed-point global accumulation
    double hrEd = wave_reduce((double)hrE);
    double ecd  = wave_reduce((double)ec);
    if ((tid & 63) == 0) {
        long long fx = (long long)__double2ll_rn(hrEd * 4294967296.0);
        atomicAdd(hrE_cell, (u64)fx);
        atomicAdd(ec_cell, (u64)(long long)ecd);
    }
}

// ---------------------------------------------------------------------------
// K2: reduce u32 partials (1024 rows) -> s_fin/T_fin (double), n_fin (u32).
// 256 blocks x 8 bins; 128 j-groups, 8 rows per thread.
// ---------------------------------------------------------------------------
__global__ __launch_bounds__(RT) void k_reduce(
    const u32* __restrict__ s0_part, const u32* __restrict__ tn_part,
    double* __restrict__ s_fin, double* __restrict__ T_fin,
    unsigned* __restrict__ n_fin)
{
    __shared__ u64      rs[128][8];    // 8 KB
    __shared__ u64      rt[128][8];    // 8 KB
    __shared__ unsigned rn[128][8];    // 4 KB
    __shared__ u64      ps[8][2], pt[8][2];
    __shared__ unsigned pn[8][2];

    const int bi = threadIdx.x & 7;
    const int jg = threadIdx.x >> 3;          // 0..127
    const int t  = blockIdx.x * 8 + bi;

    u64 s = 0ull, T = 0ull;
    unsigned c = 0u;
#pragma unroll
    for (int m = 0; m < HB / 128; ++m) {      // 8 rows per thread
        int j = jg + (m << 7);
        size_t idx = (size_t)j * NT + t;
        s += s0_part[idx];
        u32 v = tn_part[idx];
        T += v & TM26;
        c += v >> 26;
    }
    rs[jg][bi] = s; rt[jg][bi] = T; rn[jg][bi] = c;
    __syncthreads();

    const int wv  = threadIdx.x >> 6;         // 0..15
    const int l   = threadIdx.x & 63;
    const int bin = wv >> 1;
    const int hf  = wv & 1;
    u64 S  = rs[hf * 64 + l][bin];
    u64 TT = rt[hf * 64 + l][bin];
    u64 C  = rn[hf * 64 + l][bin];
#pragma unroll
    for (int o = 32; o > 0; o >>= 1) {
        S  += __shfl_down(S,  o, 64);
        TT += __shfl_down(TT, o, 64);
        C  += __shfl_down(C,  o, 64);
    }
    if (l == 0) { ps[bin][hf] = S; pt[bin][hf] = TT; pn[bin][hf] = (unsigned)C; }
    __syncthreads();
    if (threadIdx.x < 8) {
        int b = threadIdx.x;
        u64 S2  = ps[b][0] + ps[b][1];
        u64 TT2 = pt[b][0] + pt[b][1];
        unsigned C2 = pn[b][0] + pn[b][1];
        int tt = blockIdx.x * 8 + b;
        s_fin[tt] = (double)(S2 + TT2) * INV_SC;   // s = s0 + T
        T_fin[tt] = (double)TT2 * INV_SC;
        n_fin[tt] = C2;
    }
}

// ---------------------------------------------------------------------------
// K3: each block redundantly suffix-scans s_fin (2048 doubles) in LDS, does
// the Efron correction for its 16 bins (one wave per bin), then the LAST
// block (ticket atomic) reduces corr and writes the loss.
// ---------------------------------------------------------------------------
__global__ __launch_bounds__(ET) void k_scan_efron_final(
    const double* __restrict__ s_fin, const double* __restrict__ T_fin,
    const unsigned* __restrict__ n_fin,
    double* __restrict__ corr_part,
    const u64* __restrict__ hrE_cell, const u64* __restrict__ ec_cell,
    unsigned* __restrict__ counter, float* __restrict__ out)
{
    __shared__ double sa[NT];
    __shared__ double sb[NT];
    __shared__ double red[16];
    __shared__ double redA[16];
    __shared__ unsigned is_last;

    const int tid = threadIdx.x, bid = blockIdx.x;

    // --- suffix scan (Hillis-Steele, ping-pong) ---
    for (int i = tid; i < NT; i += ET) sa[i] = s_fin[i];
    __syncthreads();
    double* cur = sa;
    double* nxt = sb;
    for (int off = 1; off < NT; off <<= 1) {
        for (int i = tid; i < NT; i += ET) {
            double v = cur[i];
            if (i + off < NT) v += cur[i + off];
            nxt[i] = v;
        }
        __syncthreads();
        double* tmp = cur; cur = nxt; nxt = tmp;
    }

    // --- Efron correction: one wave per bin, 16 bins per block ---
    const int wv = tid >> 6;
    const int l  = tid & 63;
    const int t  = bid * 16 + wv;
    unsigned nt = n_fin[t];
    double acc = 0.0;
    if (nt > 0) {
        double Rt = cur[t];
        double Tt = T_fin[t];
        double inv = 1.0 / (double)nt;
        for (unsigned k = l; k < nt; k += 64)
            acc += (double)logf((float)(Rt - (double)k * inv * Tt));
    }
    acc = wave_reduce(acc);
    if (l == 0) red[wv] = acc;
    __syncthreads();
    if (tid == 0) {
        double c = 0.0;
#pragma unroll
        for (int m = 0; m < 16; ++m) c += red[m];
        corr_part[bid] = c;
    }
    __syncthreads();

    // --- last-block final reduction ---
    if (tid == 0) {
        __threadfence();
        unsigned ticket = atomicAdd(counter, 1u);
        is_last = (ticket == EB - 1) ? 1u : 0u;
    }
    __syncthreads();
    if (is_last) {
        __threadfence();
        double a = (tid < EB) ? corr_part[tid] : 0.0;
        a = wave_reduce(a);
        if ((tid & 63) == 0) redA[tid >> 6] = a;
        __syncthreads();
        if (tid == 0) {
            double A = 0.0;
#pragma unroll
            for (int w = 0; w < 16; ++w) A += redA[w];
            double H = (double)(long long)(*hrE_cell) * INV32;
            double C = (double)(long long)(*ec_cell);
            out[0] = (float)(-(H - A) / (C + 1e-7));
        }
    }
}

// ---------------------------------------------------------------------------
extern "C" void kernel_launch(void* const* d_in, const int* in_sizes, int n_in,
                              void* d_out, int out_size, void* d_ws, size_t ws_size,
                              hipStream_t stream)
{
    const float* hr  = (const float*)d_in[0];
    const int*   dur = (const int*)d_in[1];
    const int*   ev  = (const int*)d_in[2];
    int n = in_sizes[1];

    char* ws = (char*)d_ws;
    u32*      s0_part   = (u32*)ws;                                   // 1024*2048*4 = 8 MB
    u32*      tn_part   = (u32*)(ws + (size_t)8 * 1024 * 1024);       // 8 MB
    char*     p         = ws + (size_t)16 * 1024 * 1024;
    double*   s_fin     = (double*)p;          p += NT * 8;
    double*   T_fin     = (double*)p;          p += NT * 8;
    unsigned* n_fin     = (unsigned*)p;        p += NT * 4;
    double*   corr_part = (double*)p;          p += EB * 8;
    u64*      hrE_cell  = (u64*)p;             p += 8;
    u64*      ec_cell   = (u64*)p;             p += 8;
    unsigned* counter   = (unsigned*)p;        p += 4;

    // zero the atomic cells + ticket counter (24 B) each call
    hipMemsetAsync((void*)hrE_cell, 0, 24, stream);

    hipLaunchKernelGGL(k_hist, dim3(HB), dim3(HT), 0, stream,
                       hr, dur, ev, n, s0_part, tn_part, hrE_cell, ec_cell);
    hipLaunchKernelGGL(k_reduce, dim3(RB), dim3(RT), 0, stream,
                       s0_part, tn_part, s_fin, T_fin, n_fin);
    hipLaunchKernelGGL(k_scan_efron_final, dim3(EB), dim3(ET), 0, stream,
                       s_fin, T_fin, n_fin, corr_part, hrE_cell, ec_cell,
                       counter, (float*)d_out);
}

// Round 9
// 47.648 us; speedup vs baseline: 5.1035x; 5.1035x over previous
//
#include <hip/hip_runtime.h>

#define NT 2048            // number of distinct event times
#define HB 1024            // hist blocks (4 per CU)
#define HT 512             // hist threads per block (8 waves)
#define RB 256             // reduce blocks (8 bins each)
#define RT 1024
#define EB 128             // efron blocks (16 bins each, 1 wave per bin)
#define ET 1024

#define SC      4096.0f              // 2^12 fixed-point scale (exact pow2 mult)
#define INV_SC  (1.0 / 4096.0)
#define TM26    ((1u << 26) - 1)     // tn pack: low 26 bits T, high 6 bits count

typedef unsigned long long u64;
typedef unsigned u32;

__device__ __forceinline__ double wave_reduce(double v) {
#pragma unroll
    for (int o = 32; o > 0; o >>= 1) v += __shfl_down(v, o, 64);
    return v;
}

// ---------------------------------------------------------------------------
// K1: LDS histogram at 32 waves/CU (4 blocks x 8 waves, <=64 VGPR).
// Exactly 2 vec4 iterations per thread, all 6x16B loads staged up front.
// One u32 LDS atomic per sample: loc[d + e*NT] += fx + (e<<26).
// hr*e / e sums: per-wave shuffle reduce -> per-block LDS reduce -> STORE
// (no global atomics -- round 8 measured 12.5 ns per same-address atomic).
// ---------------------------------------------------------------------------
__global__ __launch_bounds__(HT, 8) void k_hist(
    const float* __restrict__ hr, const int* __restrict__ dur,
    const int* __restrict__ ev, int n,
    u32* __restrict__ s0_part, u32* __restrict__ tn_part,
    double* __restrict__ hrE_part, double* __restrict__ eCnt_part,
    unsigned* __restrict__ counter)
{
    __shared__ u32    loc[2 * NT];      // 16 KB
    __shared__ double redH[HT / 64], redC[HT / 64];

    const int tid = threadIdx.x, bid = blockIdx.x;
    if (bid == 0 && tid == 0) *counter = 0u;   // ticket for K3

    for (int i = tid; i < 2 * NT; i += HT) loc[i] = 0u;
    __syncthreads();

    float hrE = 0.f;
    int   ec  = 0;
    const int stride = HB * HT;      // 524288
    const int nv = n >> 2;           // 1048576
    const float4* hr4 = (const float4*)hr;
    const int4*   d4p = (const int4*)dur;
    const int4*   e4p = (const int4*)ev;

    auto process = [&](const float4& h, const int4& d, const int4& e) {
        float hh[4] = { h.x, h.y, h.z, h.w };
        int   dd[4] = { d.x, d.y, d.z, d.w };
        int   ee[4] = { e.x, e.y, e.z, e.w };
#pragma unroll
        for (int u = 0; u < 4; ++u) {
            float eh = __expf(hh[u]);
            u32 fx = (u32)(eh * SC + 0.5f);
            atomicAdd(&loc[dd[u] + (ee[u] << 11)], fx + ((u32)ee[u] << 26));
            hrE += hh[u] * (float)ee[u];
            ec  += ee[u];
        }
    };

    // n = 2^22: exactly 2 vec4 iterations per thread; stage ALL loads first.
    {
        int i0 = bid * HT + tid;
        int i1 = i0 + stride;
        if (i1 < nv) {                       // common case: both iterations
            float4 h0 = hr4[i0]; int4 d0 = d4p[i0]; int4 e0 = e4p[i0];
            float4 h1 = hr4[i1]; int4 d1 = d4p[i1]; int4 e1 = e4p[i1];
            process(h0, d0, e0);
            process(h1, d1, e1);
        } else {
            for (int i = i0; i < nv; i += stride)
                process(hr4[i], d4p[i], e4p[i]);
        }
    }
    for (int j = (nv << 2) + bid * HT + tid; j < n; j += stride) {  // tail
        float h = hr[j]; int d = dur[j]; int e = ev[j];
        atomicAdd(&loc[d + (e << 11)], (u32)(__expf(h) * SC + 0.5f) + ((u32)e << 26));
        hrE += h * (float)e;
        ec  += e;
    }
    __syncthreads();

    // write per-block partial rows (streaming, coalesced)
    const size_t base = (size_t)bid * NT;
    for (int k = tid; k < NT; k += HT) {
        s0_part[base + k] = loc[k];
        tn_part[base + k] = loc[NT + k];
    }

    // per-block hr*e / e sums, plain stores
    double hrEd = wave_reduce((double)hrE);
    double ecd  = wave_reduce((double)ec);
    if ((tid & 63) == 0) { redH[tid >> 6] = hrEd; redC[tid >> 6] = ecd; }
    __syncthreads();
    if (tid == 0) {
        double hh = 0.0, cc = 0.0;
#pragma unroll
        for (int w = 0; w < HT / 64; ++w) { hh += redH[w]; cc += redC[w]; }
        hrE_part[bid]  = hh;
        eCnt_part[bid] = cc;
    }
}

// ---------------------------------------------------------------------------
// K2: reduce u32 partials (1024 rows) -> s_fin/T_fin (double), n_fin (u32).
// 256 blocks x 8 bins; 128 j-groups, 8 rows per thread.
// ---------------------------------------------------------------------------
__global__ __launch_bounds__(RT) void k_reduce(
    const u32* __restrict__ s0_part, const u32* __restrict__ tn_part,
    double* __restrict__ s_fin, double* __restrict__ T_fin,
    unsigned* __restrict__ n_fin)
{
    __shared__ u64      rs[128][8];    // 8 KB
    __shared__ u64      rt[128][8];    // 8 KB
    __shared__ unsigned rn[128][8];    // 4 KB
    __shared__ u64      ps[8][2], pt[8][2];
    __shared__ unsigned pn[8][2];

    const int bi = threadIdx.x & 7;
    const int jg = threadIdx.x >> 3;          // 0..127
    const int t  = blockIdx.x * 8 + bi;

    u64 s = 0ull, T = 0ull;
    unsigned c = 0u;
#pragma unroll
    for (int m = 0; m < HB / 128; ++m) {      // 8 rows per thread
        int j = jg + (m << 7);
        size_t idx = (size_t)j * NT + t;
        s += s0_part[idx];
        u32 v = tn_part[idx];
        T += v & TM26;
        c += v >> 26;
    }
    rs[jg][bi] = s; rt[jg][bi] = T; rn[jg][bi] = c;
    __syncthreads();

    const int wv  = threadIdx.x >> 6;         // 0..15
    const int l   = threadIdx.x & 63;
    const int bin = wv >> 1;
    const int hf  = wv & 1;
    u64 S  = rs[hf * 64 + l][bin];
    u64 TT = rt[hf * 64 + l][bin];
    u64 C  = rn[hf * 64 + l][bin];
#pragma unroll
    for (int o = 32; o > 0; o >>= 1) {
        S  += __shfl_down(S,  o, 64);
        TT += __shfl_down(TT, o, 64);
        C  += __shfl_down(C,  o, 64);
    }
    if (l == 0) { ps[bin][hf] = S; pt[bin][hf] = TT; pn[bin][hf] = (unsigned)C; }
    __syncthreads();
    if (threadIdx.x < 8) {
        int b = threadIdx.x;
        u64 S2  = ps[b][0] + ps[b][1];
        u64 TT2 = pt[b][0] + pt[b][1];
        unsigned C2 = pn[b][0] + pn[b][1];
        int tt = blockIdx.x * 8 + b;
        s_fin[tt] = (double)(S2 + TT2) * INV_SC;   // s = s0 + T
        T_fin[tt] = (double)TT2 * INV_SC;
        n_fin[tt] = C2;
    }
}

// ---------------------------------------------------------------------------
// K3: each block redundantly suffix-scans s_fin (2048 doubles) in LDS, does
// the Efron correction for its 16 bins (one wave per bin), then the LAST
// block (ticket atomic) reduces corr + hrE/eCnt partials and writes the loss.
// ---------------------------------------------------------------------------
__global__ __launch_bounds__(ET) void k_scan_efron_final(
    const double* __restrict__ s_fin, const double* __restrict__ T_fin,
    const unsigned* __restrict__ n_fin,
    double* __restrict__ corr_part, const double* __restrict__ hrE_part,
    const double* __restrict__ eCnt_part,
    unsigned* __restrict__ counter, float* __restrict__ out)
{
    __shared__ double sa[NT];
    __shared__ double sb[NT];
    __shared__ double red[16];
    __shared__ unsigned is_last;

    const int tid = threadIdx.x, bid = blockIdx.x;

    // --- suffix scan (Hillis-Steele, ping-pong) ---
    for (int i = tid; i < NT; i += ET) sa[i] = s_fin[i];
    __syncthreads();
    double* cur = sa;
    double* nxt = sb;
    for (int off = 1; off < NT; off <<= 1) {
        for (int i = tid; i < NT; i += ET) {
            double v = cur[i];
            if (i + off < NT) v += cur[i + off];
            nxt[i] = v;
        }
        __syncthreads();
        double* tmp = cur; cur = nxt; nxt = tmp;
    }

    // --- Efron correction: one wave per bin, 16 bins per block ---
    const int wv = tid >> 6;
    const int l  = tid & 63;
    const int t  = bid * 16 + wv;
    unsigned nt = n_fin[t];
    double acc = 0.0;
    if (nt > 0) {
        double Rt = cur[t];
        double Tt = T_fin[t];
        double inv = 1.0 / (double)nt;
        for (unsigned k = l; k < nt; k += 64)
            acc += (double)logf((float)(Rt - (double)k * inv * Tt));
    }
    acc = wave_reduce(acc);
    if (l == 0) red[wv] = acc;
    __syncthreads();
    if (tid == 0) {
        double c = 0.0;
#pragma unroll
        for (int m = 0; m < 16; ++m) c += red[m];
        corr_part[bid] = c;
    }
    __syncthreads();

    // --- last-block final reduction ---
    if (tid == 0) {
        __threadfence();
        unsigned ticket = atomicAdd(counter, 1u);
        is_last = (ticket == EB - 1) ? 1u : 0u;
    }
    __syncthreads();
    if (is_last) {
        __threadfence();
        __shared__ double redA[16], redB[16], redC[16];
        double a = (tid < EB) ? corr_part[tid] : 0.0;
        double h = hrE_part[tid];          // HB == ET == 1024: one row each
        double c = eCnt_part[tid];
        a = wave_reduce(a); h = wave_reduce(h); c = wave_reduce(c);
        if ((tid & 63) == 0) { redA[tid >> 6] = a; redB[tid >> 6] = h; redC[tid >> 6] = c; }
        __syncthreads();
        if (tid == 0) {
            double A = 0.0, H = 0.0, C = 0.0;
#pragma unroll
            for (int w = 0; w < 16; ++w) { A += redA[w]; H += redB[w]; C += redC[w]; }
            out[0] = (float)(-(H - A) / (C + 1e-7));
        }
    }
}

// ---------------------------------------------------------------------------
extern "C" void kernel_launch(void* const* d_in, const int* in_sizes, int n_in,
                              void* d_out, int out_size, void* d_ws, size_t ws_size,
                              hipStream_t stream)
{
    const float* hr  = (const float*)d_in[0];
    const int*   dur = (const int*)d_in[1];
    const int*   ev  = (const int*)d_in[2];
    int n = in_sizes[1];

    char* ws = (char*)d_ws;
    u32*      s0_part   = (u32*)ws;                                   // 1024*2048*4 = 8 MB
    u32*      tn_part   = (u32*)(ws + (size_t)8 * 1024 * 1024);       // 8 MB
    char*     p         = ws + (size_t)16 * 1024 * 1024;
    double*   s_fin     = (double*)p;          p += NT * 8;
    double*   T_fin     = (double*)p;          p += NT * 8;
    unsigned* n_fin     = (unsigned*)p;        p += NT * 4;
    double*   corr_part = (double*)p;          p += EB * 8;
    double*   hrE_part  = (double*)p;          p += HB * 8;
    double*   eCnt_part = (double*)p;          p += HB * 8;
    unsigned* counter   = (unsigned*)p;        p += 4;

    hipLaunchKernelGGL(k_hist, dim3(HB), dim3(HT), 0, stream,
                       hr, dur, ev, n, s0_part, tn_part, hrE_part, eCnt_part, counter);
    hipLaunchKernelGGL(k_reduce, dim3(RB), dim3(RT), 0, stream,
                       s0_part, tn_part, s_fin, T_fin, n_fin);
    hipLaunchKernelGGL(k_scan_efron_final, dim3(EB), dim3(ET), 0, stream,
                       s_fin, T_fin, n_fin, corr_part, hrE_part, eCnt_part,
                       counter, (float*)d_out);
}

// Round 10
// 35.709 us; speedup vs baseline: 6.8097x; 1.3343x over previous
//
#include <hip/hip_runtime.h>

#define NT 2048            // number of distinct event times
#define HB 256             // hist blocks (1 per CU)
#define HT 1024            // hist threads per block (16 waves)
#define RB 256             // reduce blocks (8 bins each)
#define RT 1024
#define EB 128             // efron blocks (16 bins each, 1 wave per bin)
#define ET 1024

#define SC      4096.0f              // 2^12 fixed-point scale (exact pow2 mult)
#define INV_SC  (1.0 / 4096.0)
#define TM26    ((1u << 26) - 1)     // tn pack: low 26 bits T, high 6 bits count

typedef unsigned long long u64;
typedef unsigned u32;

__device__ __forceinline__ double wave_reduce(double v) {
#pragma unroll
    for (int o = 32; o > 0; o >>= 1) v += __shfl_down(v, o, 64);
    return v;
}

// ---------------------------------------------------------------------------
// K1: round-7 structure (dual images, prefetch pipeline, __expf) with ONE
// change: batched atomic issue — compute all 4 fx/idx first, then fire the
// 4 ds_add back-to-back (tests per-atomic program-order serialization).
// ---------------------------------------------------------------------------
__global__ __launch_bounds__(HT) void k_hist(
    const float* __restrict__ hr, const int* __restrict__ dur,
    const int* __restrict__ ev, int n,
    u32* __restrict__ s0_part, u32* __restrict__ tn_part,
    double* __restrict__ hrE_part, double* __restrict__ eCnt_part,
    unsigned* __restrict__ counter)
{
    __shared__ u32    loc[2][2 * NT];   // 32 KB, image per wave-parity
    __shared__ double redH[HT / 64], redC[HT / 64];

    const int tid = threadIdx.x, bid = blockIdx.x;
    if (bid == 0 && tid == 0) *counter = 0u;

    for (int i = tid; i < 2 * NT; i += HT) { loc[0][i] = 0u; loc[1][i] = 0u; }
    __syncthreads();

    u32* img = loc[(tid >> 6) & 1];

    float hrE = 0.f;
    int   ec  = 0;
    const int stride = HB * HT;
    const int nv = n >> 2;
    const float4* hr4 = (const float4*)hr;
    const int4*   d4p = (const int4*)dur;
    const int4*   e4p = (const int4*)ev;

    auto process = [&](const float4& h, const int4& d, const int4& e) {
        float hh[4] = { h.x, h.y, h.z, h.w };
        int   dd[4] = { d.x, d.y, d.z, d.w };
        int   ee[4] = { e.x, e.y, e.z, e.w };
        u32 val[4]; int idx[4];
#pragma unroll
        for (int u = 0; u < 4; ++u) {                  // phase 1: pure VALU
            float eh = __expf(hh[u]);
            val[u] = (u32)(eh * SC + 0.5f) + ((u32)ee[u] << 26);
            idx[u] = dd[u] + (ee[u] << 11);
        }
#pragma unroll
        for (int u = 0; u < 4; ++u)                    // phase 2: atomics only
            atomicAdd(&img[idx[u]], val[u]);
#pragma unroll
        for (int u = 0; u < 4; ++u) {                  // phase 3: accumulators
            hrE += hh[u] * (float)ee[u];
            ec  += ee[u];
        }
    };

    // n = 2^22: exactly 4 vec4 iterations; prefetch next before process(cur).
    int i = bid * HT + tid;
    if (i < nv) {
        float4 h_c = hr4[i];
        int4   d_c = d4p[i];
        int4   e_c = e4p[i];
        for (i += stride; i < nv; i += stride) {
            float4 h_n = hr4[i];
            int4   d_n = d4p[i];
            int4   e_n = e4p[i];
            process(h_c, d_c, e_c);       // overlaps with the 3 loads above
            h_c = h_n; d_c = d_n; e_c = e_n;
        }
        process(h_c, d_c, e_c);
    }
    for (int j = (nv << 2) + bid * HT + tid; j < n; j += stride) {  // tail
        float h = hr[j]; int d = dur[j]; int e = ev[j];
        float eh = __expf(h);
        atomicAdd(&loc[(tid >> 6) & 1][d + (e << 11)],
                  (u32)(eh * SC + 0.5f) + ((u32)e << 26));
        hrE += h * (float)e;
        ec  += e;
    }
    __syncthreads();

    // merge images field-wise (no cross-field carry) and write partials
    const size_t base = (size_t)bid * NT;
    for (int k = tid; k < NT; k += HT) {
        s0_part[base + k] = loc[0][k] + loc[1][k];
        u32 a = loc[0][NT + k], b = loc[1][NT + k];
        tn_part[base + k] = (((a >> 26) + (b >> 26)) << 26)
                          + ((a & TM26) + (b & TM26));
    }

    double hrEd = wave_reduce((double)hrE);
    double ecd  = wave_reduce((double)ec);
    if ((tid & 63) == 0) { redH[tid >> 6] = hrEd; redC[tid >> 6] = ecd; }
    __syncthreads();
    if (tid == 0) {
        double hh = 0.0, cc = 0.0;
#pragma unroll
        for (int w = 0; w < HT / 64; ++w) { hh += redH[w]; cc += redC[w]; }
        hrE_part[bid]  = hh;
        eCnt_part[bid] = cc;
    }
}

// ---------------------------------------------------------------------------
// K2: reduce u32 partials (256 rows) -> s_fin/T_fin (double), n_fin (u32).
// 256 blocks x 8 bins; 128 j-groups x 8 bins, 2 rows per thread, coalesced.
// ---------------------------------------------------------------------------
__global__ __launch_bounds__(RT) void k_reduce(
    const u32* __restrict__ s0_part, const u32* __restrict__ tn_part,
    double* __restrict__ s_fin, double* __restrict__ T_fin,
    unsigned* __restrict__ n_fin)
{
    __shared__ u64      rs[128][8];    // 8 KB
    __shared__ u64      rt[128][8];    // 8 KB
    __shared__ unsigned rn[128][8];    // 4 KB
    __shared__ u64      ps[8][2], pt[8][2];
    __shared__ unsigned pn[8][2];

    const int bi = threadIdx.x & 7;
    const int jg = threadIdx.x >> 3;          // 0..127
    const int t  = blockIdx.x * 8 + bi;

    u64 s = 0ull, T = 0ull;
    unsigned c = 0u;
#pragma unroll
    for (int m = 0; m < HB / 128; ++m) {      // 2 rows per thread
        int j = jg + (m << 7);
        size_t idx = (size_t)j * NT + t;
        s += s0_part[idx];
        u32 v = tn_part[idx];
        T += v & TM26;
        c += v >> 26;
    }
    rs[jg][bi] = s; rt[jg][bi] = T; rn[jg][bi] = c;
    __syncthreads();

    const int wv  = threadIdx.x >> 6;         // 0..15
    const int l   = threadIdx.x & 63;
    const int bin = wv >> 1;
    const int hf  = wv & 1;
    u64 S  = rs[hf * 64 + l][bin];
    u64 TT = rt[hf * 64 + l][bin];
    u64 C  = rn[hf * 64 + l][bin];
#pragma unroll
    for (int o = 32; o > 0; o >>= 1) {
        S  += __shfl_down(S,  o, 64);
        TT += __shfl_down(TT, o, 64);
        C  += __shfl_down(C,  o, 64);
    }
    if (l == 0) { ps[bin][hf] = S; pt[bin][hf] = TT; pn[bin][hf] = (unsigned)C; }
    __syncthreads();
    if (threadIdx.x < 8) {
        int b = threadIdx.x;
        u64 S2  = ps[b][0] + ps[b][1];
        u64 TT2 = pt[b][0] + pt[b][1];
        unsigned C2 = pn[b][0] + pn[b][1];
        int tt = blockIdx.x * 8 + b;
        s_fin[tt] = (double)(S2 + TT2) * INV_SC;   // s = s0 + T
        T_fin[tt] = (double)TT2 * INV_SC;
        n_fin[tt] = C2;
    }
}

// ---------------------------------------------------------------------------
// K3: each block redundantly suffix-scans s_fin (2048 doubles) in LDS, does
// the Efron correction for its 16 bins (one wave per bin), then the LAST
// block (ticket atomic, no spin) reduces everything and writes the loss.
// ---------------------------------------------------------------------------
__global__ __launch_bounds__(ET) void k_scan_efron_final(
    const double* __restrict__ s_fin, const double* __restrict__ T_fin,
    const unsigned* __restrict__ n_fin,
    double* __restrict__ corr_part, const double* __restrict__ hrE_part,
    const double* __restrict__ eCnt_part,
    unsigned* __restrict__ counter, float* __restrict__ out)
{
    __shared__ double sa[NT];
    __shared__ double sb[NT];
    __shared__ double red[16];
    __shared__ unsigned is_last;

    const int tid = threadIdx.x, bid = blockIdx.x;

    // --- suffix scan (Hillis-Steele, ping-pong) ---
    for (int i = tid; i < NT; i += ET) sa[i] = s_fin[i];
    __syncthreads();
    double* cur = sa;
    double* nxt = sb;
    for (int off = 1; off < NT; off <<= 1) {
        for (int i = tid; i < NT; i += ET) {
            double v = cur[i];
            if (i + off < NT) v += cur[i + off];
            nxt[i] = v;
        }
        __syncthreads();
        double* tmp = cur; cur = nxt; nxt = tmp;
    }

    // --- Efron correction: one wave per bin, 16 bins per block ---
    const int wv = tid >> 6;
    const int l  = tid & 63;
    const int t  = bid * 16 + wv;
    unsigned nt = n_fin[t];
    double acc = 0.0;
    if (nt > 0) {
        double Rt = cur[t];
        double Tt = T_fin[t];
        double inv = 1.0 / (double)nt;
        for (unsigned k = l; k < nt; k += 64)
            acc += (double)logf((float)(Rt - (double)k * inv * Tt));
    }
    acc = wave_reduce(acc);
    if (l == 0) red[wv] = acc;
    __syncthreads();
    if (tid == 0) {
        double c = 0.0;
#pragma unroll
        for (int m = 0; m < 16; ++m) c += red[m];
        corr_part[bid] = c;
    }
    __syncthreads();

    // --- last-block final reduction ---
    if (tid == 0) {
        __threadfence();
        unsigned ticket = atomicAdd(counter, 1u);
        is_last = (ticket == EB - 1) ? 1u : 0u;
    }
    __syncthreads();
    if (is_last) {
        __threadfence();
        __shared__ double redA[16], redB[16], redC[16];
        double a = (tid < EB) ? corr_part[tid] : 0.0;
        double h = 0.0, c = 0.0;
        if (tid < HB) { h = hrE_part[tid]; c = eCnt_part[tid]; }
        a = wave_reduce(a); h = wave_reduce(h); c = wave_reduce(c);
        if ((tid & 63) == 0) { redA[tid >> 6] = a; redB[tid >> 6] = h; redC[tid >> 6] = c; }
        __syncthreads();
        if (tid == 0) {
            double A = 0.0, H = 0.0, C = 0.0;
#pragma unroll
            for (int w = 0; w < 16; ++w) { A += redA[w]; H += redB[w]; C += redC[w]; }
            out[0] = (float)(-(H - A) / (C + 1e-7));
        }
    }
}

// ---------------------------------------------------------------------------
extern "C" void kernel_launch(void* const* d_in, const int* in_sizes, int n_in,
                              void* d_out, int out_size, void* d_ws, size_t ws_size,
                              hipStream_t stream)
{
    const float* hr  = (const float*)d_in[0];
    const int*   dur = (const int*)d_in[1];
    const int*   ev  = (const int*)d_in[2];
    int n = in_sizes[1];

    char* ws = (char*)d_ws;
    u32*      s0_part   = (u32*)ws;                                  // 256*2048*4 = 2 MB
    u32*      tn_part   = (u32*)(ws + (size_t)2 * 1024 * 1024);      // 2 MB
    char*     p         = ws + (size_t)4 * 1024 * 1024;
    double*   s_fin     = (double*)p;          p += NT * 8;
    double*   T_fin     = (double*)p;          p += NT * 8;
    unsigned* n_fin     = (unsigned*)p;        p += NT * 4;
    double*   corr_part = (double*)p;          p += EB * 8;
    double*   hrE_part  = (double*)p;          p += HB * 8;
    double*   eCnt_part = (double*)p;          p += HB * 8;
    unsigned* counter   = (unsigned*)p;

    hipLaunchKernelGGL(k_hist, dim3(HB), dim3(HT), 0, stream,
                       hr, dur, ev, n, s0_part, tn_part, hrE_part, eCnt_part, counter);
    hipLaunchKernelGGL(k_reduce, dim3(RB), dim3(RT), 0, stream,
                       s0_part, tn_part, s_fin, T_fin, n_fin);
    hipLaunchKernelGGL(k_scan_efron_final, dim3(EB), dim3(ET), 0, stream,
                       s_fin, T_fin, n_fin, corr_part, hrE_part, eCnt_part,
                       counter, (float*)d_out);
}